// Round 2
// baseline (278.488 us; speedup 1.0000x reference)
//
#include <hip/hip_runtime.h>

#define NB   16
#define NSQ  1024
#define NSKV 1024
#define ND   256

typedef __bf16 bf16x4 __attribute__((ext_vector_type(4)));
typedef __bf16 bf16x8 __attribute__((ext_vector_type(8)));
typedef float  f32x4  __attribute__((ext_vector_type(4)));

#define LDS_STRIDE 264   // bf16 elems/row: 528 B -> 2-way bank aliasing (free)

// Grid: NB*64 blocks, one per 16 q-rows. 4 waves/block; wave w owns k-quarter
// [w*256, w*256+256). Wave-private LDS staging => no barriers in main loops.
// Pass A: S=QK^T (mfma 16x16x32 bf16), e = mask?exp(exp(S)/16):0, Z+=e,
//         mask bit saved per (row,chunk) in registers.
// Z combined across the 4 waves via LDS (single __syncthreads).
// Pass B: re-stage K (L2/L3 hot), recompute S and e, p = e/Z, write p once,
//         column sums reduced in-wave then one coalesced atomic per 16 cols.
__global__ __launch_bounds__(256, 4) void attn_fused(
    const float* __restrict__ Q, const float* __restrict__ K,
    const int* __restrict__ mask, float* __restrict__ out_p,
    float* __restrict__ colsum)
{
    const int b    = blockIdx.x >> 6;
    const int qt   = blockIdx.x & 63;
    const int q0   = qt * 16;
    const int tid  = threadIdx.x;
    const int lane = tid & 63;
    const int w    = tid >> 6;        // wave id = k-quarter
    const int m    = lane & 15;       // MFMA A-row / B-col / C-col
    const int kg   = lane >> 4;       // quad: k-slice for A/B, row-group for C

    __shared__ __bf16 Ks[4][16 * LDS_STRIDE];  // per-wave 16-row K chunk
    __shared__ float  Zs[4][16];

    // ---- A fragments: the block's 16 Q rows (same for every wave) ----
    bf16x8 afrag[8];
    {
        const float* qbase = Q + ((size_t)(b * NSQ + q0 + m)) * ND;
        #pragma unroll
        for (int dc = 0; dc < 8; ++dc) {
            const float* p4 = qbase + dc * 32 + kg * 8;
            float4 x = *(const float4*)(p4);
            float4 y = *(const float4*)(p4 + 4);
            bf16x8 a;
            a[0] = (__bf16)x.x; a[1] = (__bf16)x.y; a[2] = (__bf16)x.z; a[3] = (__bf16)x.w;
            a[4] = (__bf16)y.x; a[5] = (__bf16)y.y; a[6] = (__bf16)y.z; a[7] = (__bf16)y.w;
            afrag[dc] = a;
        }
    }

    const int k0 = w * 256;
    __bf16* myK = Ks[w];
    const float4* kquarter = (const float4*)(K + ((size_t)(b * NSKV + k0)) * ND);
    const size_t rowbase = (size_t)(b * NSQ + q0 + kg * 4);  // lane's first C row

    // ---------------- Pass A: Z + mask bits ----------------
    float    zacc[4]  = {0.f, 0.f, 0.f, 0.f};
    unsigned mbits[4] = {0u, 0u, 0u, 0u};

    for (int c = 0; c < 16; ++c) {
        // stage 16 K rows [k0+c*16, +16) into wave-private LDS as bf16
        #pragma unroll
        for (int j = 0; j < 16; ++j) {
            float4 v = kquarter[(c * 16 + j) * 64 + lane];
            bf16x4 t;
            t[0] = (__bf16)v.x; t[1] = (__bf16)v.y;
            t[2] = (__bf16)v.z; t[3] = (__bf16)v.w;
            *(bf16x4*)&myK[j * LDS_STRIDE + lane * 4] = t;
        }
        f32x4 acc = {0.f, 0.f, 0.f, 0.f};
        #pragma unroll
        for (int dc = 0; dc < 8; ++dc) {
            bf16x8 bfr = *(const bf16x8*)&myK[m * LDS_STRIDE + dc * 32 + kg * 8];
            acc = __builtin_amdgcn_mfma_f32_16x16x32_bf16(afrag[dc], bfr, acc, 0, 0, 0);
        }
        const int kcol = k0 + c * 16 + m;
        #pragma unroll
        for (int i = 0; i < 4; ++i) {
            int mk = mask[(rowbase + i) * NSKV + kcol];
            float e = mk ? __expf(__expf(acc[i]) * 0.0625f) : 0.f;
            zacc[i] += e;
            mbits[i] |= (mk ? 1u : 0u) << c;
        }
    }

    // ---- combine Z: reduce over 16 m-lanes, then across the 4 waves ----
    #pragma unroll
    for (int i = 0; i < 4; ++i) {
        float z = zacc[i];
        z += __shfl_xor(z, 1);
        z += __shfl_xor(z, 2);
        z += __shfl_xor(z, 4);
        z += __shfl_xor(z, 8);
        if (m == 0) Zs[w][kg * 4 + i] = z;
    }
    __syncthreads();
    float invZ[4];
    #pragma unroll
    for (int i = 0; i < 4; ++i) {
        const int r = kg * 4 + i;
        invZ[i] = 1.0f / (Zs[0][r] + Zs[1][r] + Zs[2][r] + Zs[3][r]);
    }

    // ---------------- Pass B: recompute, normalize, write ----------------
    for (int c = 0; c < 16; ++c) {
        #pragma unroll
        for (int j = 0; j < 16; ++j) {
            float4 v = kquarter[(c * 16 + j) * 64 + lane];
            bf16x4 t;
            t[0] = (__bf16)v.x; t[1] = (__bf16)v.y;
            t[2] = (__bf16)v.z; t[3] = (__bf16)v.w;
            *(bf16x4*)&myK[j * LDS_STRIDE + lane * 4] = t;
        }
        f32x4 acc = {0.f, 0.f, 0.f, 0.f};
        #pragma unroll
        for (int dc = 0; dc < 8; ++dc) {
            bf16x8 bfr = *(const bf16x8*)&myK[m * LDS_STRIDE + dc * 32 + kg * 8];
            acc = __builtin_amdgcn_mfma_f32_16x16x32_bf16(afrag[dc], bfr, acc, 0, 0, 0);
        }
        const int kcol = k0 + c * 16 + m;
        float csum = 0.f;
        #pragma unroll
        for (int i = 0; i < 4; ++i) {
            float e = ((mbits[i] >> c) & 1u) ? __expf(__expf(acc[i]) * 0.0625f) : 0.f;
            float p = e * invZ[i];
            out_p[(rowbase + i) * NSKV + kcol] = p;
            csum += p;
        }
        csum += __shfl_xor(csum, 16);
        csum += __shfl_xor(csum, 32);
        if (kg == 0) atomicAdd(&colsum[b * NSKV + kcol], csum);
    }
}

// out[b,d] = sum_k colsum[b,k] * V[b,k,d]; 1024 blocks, 16 k-rows each.
__global__ __launch_bounds__(256) void attn_out_kernel(
    const float* __restrict__ colsum, const float* __restrict__ V,
    float* __restrict__ out)
{
    const int b  = blockIdx.x >> 6;
    const int ks = (blockIdx.x & 63) << 4;
    const int d  = threadIdx.x;
    float acc = 0.f;
    #pragma unroll
    for (int k = 0; k < 16; ++k) {
        acc += colsum[b * NSKV + ks + k] * V[((size_t)(b * NSKV + ks + k)) * ND + d];
    }
    atomicAdd(&out[b * ND + d], acc);
}

extern "C" void kernel_launch(void* const* d_in, const int* in_sizes, int n_in,
                              void* d_out, int out_size, void* d_ws, size_t ws_size,
                              hipStream_t stream)
{
    (void)in_sizes; (void)n_in; (void)out_size; (void)ws_size;
    const float* Q    = (const float*)d_in[0];
    const float* K    = (const float*)d_in[1];
    const float* V    = (const float*)d_in[2];
    const int*   mask = (const int*)d_in[3];

    float* out0   = (float*)d_out;          // (B, D) = 4096 floats
    float* p      = out0 + NB * ND;         // p_attn (B, SQ, SKV)
    float* colsum = (float*)d_ws;           // (B, SKV)

    hipMemsetAsync(colsum, 0, NB * NSKV * sizeof(float), stream);
    hipMemsetAsync(out0, 0, NB * ND * sizeof(float), stream);

    attn_fused<<<NB * 64, 256, 0, stream>>>(Q, K, mask, p, colsum);
    attn_out_kernel<<<NB * 64, 256, 0, stream>>>(colsum, V, out0);
}

// Round 3
// 260.834 us; speedup vs baseline: 1.0677x; 1.0677x over previous
//
#include <hip/hip_runtime.h>

#define NB   16
#define NSQ  1024
#define NSKV 1024
#define ND   256

typedef __bf16    bf16x4 __attribute__((ext_vector_type(4)));
typedef __bf16    bf16x8 __attribute__((ext_vector_type(8)));
typedef float     f32x4  __attribute__((ext_vector_type(4)));
typedef _Float16  f16x4  __attribute__((ext_vector_type(4)));

#define LDS_STRIDE 264   // bf16 elems/row: 528 B -> 2-way bank aliasing (free)

// One fused kernel: block = 512 threads (8 waves), 32 q-rows, full k.
// Wave w: r = w&1 (q row-group, 16 rows), h = w>>1 (k-quarter, 256 k).
// Main loop (16 iters, fully unrolled): each h-group (2 waves, 128 thr)
// stages its 16-row K chunk into LDS (bf16), 8 MFMA 16x16x32, epilogue
// computes e = mask ? exp(exp(S)/16) : 0, accumulates Z, and PARKS e in
// registers as f16 (16 x f16x4 = 32 VGPRs). After one Z-combine barrier,
// p = e * invZ is written exactly once from registers. No recompute, no
// global round-trip. colsum accumulated via shfl-reduce + atomics.
__global__ __launch_bounds__(512, 4) void attn_fused(
    const float* __restrict__ Q, const float* __restrict__ K,
    const int* __restrict__ mask, float* __restrict__ out_p,
    float* __restrict__ colsum)
{
    const int b    = blockIdx.x >> 5;
    const int qt   = blockIdx.x & 31;
    const int q0   = qt * 32;
    const int tid  = threadIdx.x;
    const int lane = tid & 63;
    const int w    = tid >> 6;
    const int r    = w & 1;          // q row-group
    const int h    = w >> 1;         // k-quarter
    const int m    = lane & 15;      // MFMA A-row / B-col / C-col
    const int kg   = lane >> 4;      // quad: d-slice for A/B, row-group for C
    const int t128 = tid & 127;      // index within h-group (2 waves)

    __shared__ __bf16 Ks[4][16 * LDS_STRIDE];  // per-h-group 16-row K chunk
    __shared__ float  Zs[8][16];

    // ---- A fragments: this wave's 16 Q rows (f32 -> bf16, reg-resident) ----
    bf16x8 afrag[8];
    {
        const float* qbase = Q + ((size_t)(b * NSQ + q0 + r * 16 + m)) * ND;
        #pragma unroll
        for (int dc = 0; dc < 8; ++dc) {
            const float* p4 = qbase + dc * 32 + kg * 8;
            float4 x = *(const float4*)(p4);
            float4 y = *(const float4*)(p4 + 4);
            bf16x8 a;
            a[0] = (__bf16)x.x; a[1] = (__bf16)x.y; a[2] = (__bf16)x.z; a[3] = (__bf16)x.w;
            a[4] = (__bf16)y.x; a[5] = (__bf16)y.y; a[6] = (__bf16)y.z; a[7] = (__bf16)y.w;
            afrag[dc] = a;
        }
    }

    // K rows for this h-group start at b*NSKV + h*256
    const float4* kq = (const float4*)(K + ((size_t)(b * NSKV + h * 256)) * ND);
    __bf16* myK = Ks[h];
    const size_t rowbase = (size_t)(b * NSQ + q0 + r * 16 + kg * 4); // first C row

    float zacc[4] = {0.f, 0.f, 0.f, 0.f};
    f16x4 ebuf[16];

    #pragma unroll
    for (int c = 0; c < 16; ++c) {
        // mask prefetch for this chunk (latency hides under staging + MFMA)
        const int kcol = h * 256 + c * 16 + m;
        int msk[4];
        #pragma unroll
        for (int i = 0; i < 4; ++i) msk[i] = mask[(rowbase + i) * NSKV + kcol];

        if (c > 0) __syncthreads();   // protect LDS reuse (prev ds_reads done)
        // ---- stage 16 K rows [h*256 + c*16, +16) into LDS (128 threads) ----
        #pragma unroll
        for (int i = 0; i < 8; ++i) {
            int   f    = t128 + i * 128;
            int   j    = f >> 6;
            int   col4 = f & 63;
            float4 v = kq[(c * 16 + j) * 64 + col4];
            bf16x4 t;
            t[0] = (__bf16)v.x; t[1] = (__bf16)v.y;
            t[2] = (__bf16)v.z; t[3] = (__bf16)v.w;
            *(bf16x4*)&myK[j * LDS_STRIDE + col4 * 4] = t;
        }
        __syncthreads();

        f32x4 acc = {0.f, 0.f, 0.f, 0.f};
        #pragma unroll
        for (int dc = 0; dc < 8; ++dc) {
            bf16x8 bfr = *(const bf16x8*)&myK[m * LDS_STRIDE + dc * 32 + kg * 8];
            acc = __builtin_amdgcn_mfma_f32_16x16x32_bf16(afrag[dc], bfr, acc, 0, 0, 0);
        }

        #pragma unroll
        for (int i = 0; i < 4; ++i) {
            float e = msk[i] ? __expf(__expf(acc[i]) * 0.0625f) : 0.f;
            zacc[i] += e;
            ebuf[c][i] = (_Float16)e;
        }
    }

    // ---- Z: reduce over the 16 m-lanes, then combine the 4 k-quarters ----
    #pragma unroll
    for (int i = 0; i < 4; ++i) {
        float z = zacc[i];
        z += __shfl_xor(z, 1);
        z += __shfl_xor(z, 2);
        z += __shfl_xor(z, 4);
        z += __shfl_xor(z, 8);
        if (m == 0) Zs[w][kg * 4 + i] = z;
    }
    __syncthreads();
    float invZ[4];
    #pragma unroll
    for (int i = 0; i < 4; ++i) {
        const int row16 = kg * 4 + i;
        invZ[i] = 1.0f / (Zs[r][row16] + Zs[r + 2][row16] +
                          Zs[r + 4][row16] + Zs[r + 6][row16]);
    }

    // ---- write p once from registers; accumulate colsum ----
    #pragma unroll
    for (int c = 0; c < 16; ++c) {
        const int kcol = h * 256 + c * 16 + m;
        float csum = 0.f;
        #pragma unroll
        for (int i = 0; i < 4; ++i) {
            float p = (float)ebuf[c][i] * invZ[i];
            out_p[(rowbase + i) * NSKV + kcol] = p;
            csum += p;
        }
        csum += __shfl_xor(csum, 16);
        csum += __shfl_xor(csum, 32);
        if (kg == 0) atomicAdd(&colsum[b * NSKV + kcol], csum);
    }
}

// out[b,d] = sum_k colsum[b,k] * V[b,k,d]; 1024 blocks, 16 k-rows each.
__global__ __launch_bounds__(256) void attn_out_kernel(
    const float* __restrict__ colsum, const float* __restrict__ V,
    float* __restrict__ out)
{
    const int b  = blockIdx.x >> 6;
    const int ks = (blockIdx.x & 63) << 4;
    const int d  = threadIdx.x;
    float acc = 0.f;
    #pragma unroll
    for (int k = 0; k < 16; ++k) {
        acc += colsum[b * NSKV + ks + k] * V[((size_t)(b * NSKV + ks + k)) * ND + d];
    }
    atomicAdd(&out[b * ND + d], acc);
}

extern "C" void kernel_launch(void* const* d_in, const int* in_sizes, int n_in,
                              void* d_out, int out_size, void* d_ws, size_t ws_size,
                              hipStream_t stream)
{
    (void)in_sizes; (void)n_in; (void)out_size; (void)ws_size;
    const float* Q    = (const float*)d_in[0];
    const float* K    = (const float*)d_in[1];
    const float* V    = (const float*)d_in[2];
    const int*   mask = (const int*)d_in[3];

    float* out0   = (float*)d_out;          // (B, D) = 4096 floats
    float* p      = out0 + NB * ND;         // p_attn (B, SQ, SKV)
    float* colsum = (float*)d_ws;           // (B, SKV)

    hipMemsetAsync(colsum, 0, NB * NSKV * sizeof(float), stream);
    hipMemsetAsync(out0, 0, NB * ND * sizeof(float), stream);

    attn_fused<<<NB * 32, 512, 0, stream>>>(Q, K, mask, p, colsum);
    attn_out_kernel<<<NB * 64, 256, 0, stream>>>(colsum, V, out0);
}

// Round 4
// 249.750 us; speedup vs baseline: 1.1151x; 1.0444x over previous
//
#include <hip/hip_runtime.h>

#define NB   16
#define NSQ  1024
#define NSKV 1024
#define ND   256

typedef __bf16    bf16x8 __attribute__((ext_vector_type(8)));
typedef float     f32x4  __attribute__((ext_vector_type(4)));
typedef _Float16  f16x4  __attribute__((ext_vector_type(4)));

// ---- prep: convert K (f32) -> bf16, row-major, into workspace ----
__global__ __launch_bounds__(256) void cvt_k_bf16(
    const float* __restrict__ src, __bf16* __restrict__ dst)
{
    const int i = blockIdx.x * 256 + threadIdx.x;   // one bf16x8 per thread
    const float4* s = (const float4*)src + (size_t)i * 2;
    float4 a = s[0], b = s[1];
    bf16x8 o;
    o[0] = (__bf16)a.x; o[1] = (__bf16)a.y; o[2] = (__bf16)a.z; o[3] = (__bf16)a.w;
    o[4] = (__bf16)b.x; o[5] = (__bf16)b.y; o[6] = (__bf16)b.z; o[7] = (__bf16)b.w;
    ((bf16x8*)dst)[i] = o;
}

// Barrier-free main loop. Block = 256 thr (4 waves) = 16 q-rows; wave h owns
// k-quarter [h*256, +256). B-fragments for mfma_16x16x32 are CONTIGUOUS in
// K's row-major layout (lane (m,kg) needs K[base+m][dc*32+kg*8 .. +8]), so
// they load straight from the pre-converted bf16 K — no LDS, no staging
// barriers. e parked in f16 regs (64/lane = 32 VGPR); one barrier total for
// the cross-wave Z combine; p written once from registers.
__global__ __launch_bounds__(256, 4) void attn_fused(
    const float* __restrict__ Q, const __bf16* __restrict__ Kb,
    const int* __restrict__ mask, float* __restrict__ out_p,
    float* __restrict__ colsum)
{
    const int b    = blockIdx.x >> 6;
    const int qt   = blockIdx.x & 63;
    const int q0   = qt * 16;
    const int tid  = threadIdx.x;
    const int lane = tid & 63;
    const int h    = tid >> 6;       // wave id = k-quarter
    const int m    = lane & 15;      // MFMA A-row / B-col / C-col
    const int kg   = lane >> 4;      // quad: d-slice for A/B, row-group for C

    __shared__ float Zs[4][16];

    // ---- A fragments: the block's 16 Q rows, f32 -> bf16 once ----
    bf16x8 afrag[8];
    {
        const float* qbase = Q + ((size_t)(b * NSQ + q0 + m)) * ND;
        #pragma unroll
        for (int dc = 0; dc < 8; ++dc) {
            const float* p4 = qbase + dc * 32 + kg * 8;
            float4 x = *(const float4*)(p4);
            float4 y = *(const float4*)(p4 + 4);
            bf16x8 a;
            a[0] = (__bf16)x.x; a[1] = (__bf16)x.y; a[2] = (__bf16)x.z; a[3] = (__bf16)x.w;
            a[4] = (__bf16)y.x; a[5] = (__bf16)y.y; a[6] = (__bf16)y.z; a[7] = (__bf16)y.w;
            afrag[dc] = a;
        }
    }

    // this lane's B-fragment base: K row (h*256 + c*16 + m), d offset kg*8
    const __bf16* kbase = Kb + ((size_t)(b * NSKV + h * 256 + m)) * ND + kg * 8;
    const size_t rowbase = (size_t)(b * NSQ + q0 + kg * 4);   // first C row

    float zacc[4] = {0.f, 0.f, 0.f, 0.f};
    f16x4 ebuf[16];

    #pragma unroll
    for (int c = 0; c < 16; ++c) {
        const int kcol = h * 256 + c * 16 + m;
        int msk[4];
        #pragma unroll
        for (int i = 0; i < 4; ++i) msk[i] = mask[(rowbase + i) * NSKV + kcol];

        const __bf16* krow = kbase + (size_t)(c * 16) * ND;
        f32x4 acc = {0.f, 0.f, 0.f, 0.f};
        #pragma unroll
        for (int dc = 0; dc < 8; ++dc) {
            bf16x8 bfr = *(const bf16x8*)(krow + dc * 32);
            acc = __builtin_amdgcn_mfma_f32_16x16x32_bf16(afrag[dc], bfr, acc, 0, 0, 0);
        }

        #pragma unroll
        for (int i = 0; i < 4; ++i) {
            float e = msk[i] ? __expf(__expf(acc[i]) * 0.0625f) : 0.f;
            zacc[i] += e;
            ebuf[c][i] = (_Float16)e;
        }
    }

    // ---- Z: reduce over 16 m-lanes, then combine the 4 k-quarters ----
    #pragma unroll
    for (int i = 0; i < 4; ++i) {
        float z = zacc[i];
        z += __shfl_xor(z, 1);
        z += __shfl_xor(z, 2);
        z += __shfl_xor(z, 4);
        z += __shfl_xor(z, 8);
        if (m == 0) Zs[h][kg * 4 + i] = z;
    }
    __syncthreads();
    float invZ[4];
    #pragma unroll
    for (int i = 0; i < 4; ++i) {
        const int r16 = kg * 4 + i;
        invZ[i] = 1.0f / (Zs[0][r16] + Zs[1][r16] + Zs[2][r16] + Zs[3][r16]);
    }

    // ---- write p once from registers; accumulate colsum ----
    #pragma unroll
    for (int c = 0; c < 16; ++c) {
        const int kcol = h * 256 + c * 16 + m;
        float csum = 0.f;
        #pragma unroll
        for (int i = 0; i < 4; ++i) {
            float p = (float)ebuf[c][i] * invZ[i];
            out_p[(rowbase + i) * NSKV + kcol] = p;
            csum += p;
        }
        csum += __shfl_xor(csum, 16);
        csum += __shfl_xor(csum, 32);
        if (kg == 0) atomicAdd(&colsum[b * NSKV + kcol], csum);
    }
}

// out[b,d] = sum_k colsum[b,k] * V[b,k,d]; 1024 blocks, 16 k-rows each.
__global__ __launch_bounds__(256) void attn_out_kernel(
    const float* __restrict__ colsum, const float* __restrict__ V,
    float* __restrict__ out)
{
    const int b  = blockIdx.x >> 6;
    const int ks = (blockIdx.x & 63) << 4;
    const int d  = threadIdx.x;
    float acc = 0.f;
    #pragma unroll
    for (int k = 0; k < 16; ++k) {
        acc += colsum[b * NSKV + ks + k] * V[((size_t)(b * NSKV + ks + k)) * ND + d];
    }
    atomicAdd(&out[b * ND + d], acc);
}

extern "C" void kernel_launch(void* const* d_in, const int* in_sizes, int n_in,
                              void* d_out, int out_size, void* d_ws, size_t ws_size,
                              hipStream_t stream)
{
    (void)in_sizes; (void)n_in; (void)out_size; (void)ws_size;
    const float* Q    = (const float*)d_in[0];
    const float* K    = (const float*)d_in[1];
    const float* V    = (const float*)d_in[2];
    const int*   mask = (const int*)d_in[3];

    float* out0   = (float*)d_out;          // (B, D) = 4096 floats
    float* p      = out0 + NB * ND;         // p_attn (B, SQ, SKV)
    float*  colsum = (float*)d_ws;                        // 64 KB
    __bf16* Kb     = (__bf16*)((char*)d_ws + 65536);      // 8.4 MB bf16 K

    hipMemsetAsync(colsum, 0, NB * NSKV * sizeof(float), stream);
    hipMemsetAsync(out0, 0, NB * ND * sizeof(float), stream);

    const int nK8 = NB * NSKV * ND / 8;     // bf16x8 chunks
    cvt_k_bf16<<<nK8 / 256, 256, 0, stream>>>(K, Kb);
    attn_fused<<<NB * 64, 256, 0, stream>>>(Q, Kb, mask, p, colsum);
    attn_out_kernel<<<NB * 64, 256, 0, stream>>>(colsum, V, out0);
}

// Round 5
// 239.371 us; speedup vs baseline: 1.1634x; 1.0434x over previous
//
#include <hip/hip_runtime.h>

#define NB   16
#define NSQ  1024
#define NSKV 1024
#define ND   256

typedef __bf16    bf16x8 __attribute__((ext_vector_type(8)));
typedef float     f32x4  __attribute__((ext_vector_type(4)));
typedef _Float16  f16x4  __attribute__((ext_vector_type(4)));

#define ESTRIDE 264   // f16 elems per e-row (256 + 8 pad)

// ---- prep 1: K (f32) -> bf16 row-major ----
__global__ __launch_bounds__(256) void cvt_k_bf16(
    const float* __restrict__ src, __bf16* __restrict__ dst)
{
    const int i = blockIdx.x * 256 + threadIdx.x;
    const float4* s = (const float4*)src + (size_t)i * 2;
    float4 a = s[0], b = s[1];
    bf16x8 o;
    o[0] = (__bf16)a.x; o[1] = (__bf16)a.y; o[2] = (__bf16)a.z; o[3] = (__bf16)a.w;
    o[4] = (__bf16)b.x; o[5] = (__bf16)b.y; o[6] = (__bf16)b.z; o[7] = (__bf16)b.w;
    ((bf16x8*)dst)[i] = o;
}

// ---- prep 2: pack mask to bits ----
// mw[row*64 + h*16 + m], bit c = (mask[row][h*256 + c*16 + m] != 0).
// One wave per row; lane l reads cols l*16..+15, builds bits over j (=m),
// then a 16x16 bit-transpose via shuffles gives bits over c.
__global__ __launch_bounds__(256) void pack_mask(
    const int* __restrict__ mask, unsigned* __restrict__ mw)
{
    const int row = blockIdx.x * 4 + (threadIdx.x >> 6);   // b*NSQ + q
    const int l   = threadIdx.x & 63;
    const int4* mrow = (const int4*)(mask + (size_t)row * NSKV) + l * 4;
    unsigned w = 0;
    #pragma unroll
    for (int v = 0; v < 4; ++v) {
        int4 mv = mrow[v];
        w |= (mv.x != 0 ? 1u : 0u) << (v * 4 + 0);
        w |= (mv.y != 0 ? 1u : 0u) << (v * 4 + 1);
        w |= (mv.z != 0 ? 1u : 0u) << (v * 4 + 2);
        w |= (mv.w != 0 ? 1u : 0u) << (v * 4 + 3);
    }
    // lane l holds bits over m for (h = l>>4, c = l&15); emit word for
    // (h = l>>4, m = l&15) with bits over c.
    const int m    = l & 15;
    const int base = l & 48;
    unsigned out = 0;
    #pragma unroll
    for (int c = 0; c < 16; ++c) {
        unsigned v = (unsigned)__shfl((int)w, base | c);
        out |= ((v >> m) & 1u) << c;
    }
    mw[(size_t)row * 64 + l] = out;
}

// ---- main fused kernel ----
// Block = 256 thr (4 waves) = one 16-q-row tile; wave h owns k-quarter.
// All hot-loop loads are L2-class: K bf16 B-fragments direct from global
// (contiguous 16B per lane), mask = 4 pre-loaded words per lane. e parked
// in wave-private LDS (f16). After Z combine, p written as FULL 1KB
// contiguous segments per store instruction (lane->col remap via LDS).
__global__ __launch_bounds__(256, 4) void attn_fused(
    const float* __restrict__ Q, const __bf16* __restrict__ Kb,
    const unsigned* __restrict__ mw, float* __restrict__ out_p,
    float* __restrict__ colsum)
{
    const int b    = blockIdx.x >> 6;
    const int qt   = blockIdx.x & 63;
    const int q0   = qt * 16;
    const int tid  = threadIdx.x;
    const int lane = tid & 63;
    const int h    = tid >> 6;       // wave id = k-quarter
    const int m    = lane & 15;      // MFMA A-row / B-col / C-col
    const int kg   = lane >> 4;      // quad: d-slice for A/B, row-group for C

    __shared__ _Float16 Es[4][16 * ESTRIDE];   // per-wave e tile (16 x 256)
    __shared__ float    Zs[4][16];
    __shared__ float    invZs[16];

    // ---- A fragments: the block's 16 Q rows, f32 -> bf16 once ----
    bf16x8 afrag[8];
    {
        const float* qbase = Q + ((size_t)(b * NSQ + q0 + m)) * ND;
        #pragma unroll
        for (int dc = 0; dc < 8; ++dc) {
            const float* p4 = qbase + dc * 32 + kg * 8;
            float4 x = *(const float4*)(p4);
            float4 y = *(const float4*)(p4 + 4);
            bf16x8 a;
            a[0] = (__bf16)x.x; a[1] = (__bf16)x.y; a[2] = (__bf16)x.z; a[3] = (__bf16)x.w;
            a[4] = (__bf16)y.x; a[5] = (__bf16)y.y; a[6] = (__bf16)y.z; a[7] = (__bf16)y.w;
            afrag[dc] = a;
        }
    }

    // ---- mask words: 4 per lane, covers the whole loop ----
    unsigned mword[4];
    #pragma unroll
    for (int i = 0; i < 4; ++i)
        mword[i] = mw[(size_t)(b * NSQ + q0 + kg * 4 + i) * 64 + h * 16 + m];

    const __bf16* kbase = Kb + ((size_t)(b * NSKV + h * 256 + m)) * ND + kg * 8;
    _Float16* myE = Es[h];

    float zacc[4] = {0.f, 0.f, 0.f, 0.f};

    #pragma unroll
    for (int c = 0; c < 16; ++c) {
        const __bf16* krow = kbase + (size_t)(c * 16) * ND;
        f32x4 acc = {0.f, 0.f, 0.f, 0.f};
        #pragma unroll
        for (int dc = 0; dc < 8; ++dc) {
            bf16x8 bfr = *(const bf16x8*)(krow + dc * 32);
            acc = __builtin_amdgcn_mfma_f32_16x16x32_bf16(afrag[dc], bfr, acc, 0, 0, 0);
        }
        #pragma unroll
        for (int i = 0; i < 4; ++i) {
            float e = ((mword[i] >> c) & 1u) ? __expf(__expf(acc[i]) * 0.0625f) : 0.f;
            zacc[i] += e;
            myE[(kg * 4 + i) * ESTRIDE + c * 16 + m] = (_Float16)e;
        }
    }

    // ---- Z: reduce over 16 m-lanes, publish per-wave partials ----
    #pragma unroll
    for (int i = 0; i < 4; ++i) {
        float z = zacc[i];
        z += __shfl_xor(z, 1);
        z += __shfl_xor(z, 2);
        z += __shfl_xor(z, 4);
        z += __shfl_xor(z, 8);
        if (m == 0) Zs[h][kg * 4 + i] = z;
    }
    __syncthreads();
    if (tid < 16)
        invZs[tid] = 1.0f / (Zs[0][tid] + Zs[1][tid] + Zs[2][tid] + Zs[3][tid]);
    __syncthreads();

    // ---- write phase: full 1KB contiguous stores; colsum in-pass ----
    float csum[4] = {0.f, 0.f, 0.f, 0.f};
    float* prow = out_p + (size_t)(b * NSQ + q0) * NSKV + h * 256 + lane * 4;
    #pragma unroll
    for (int s = 0; s < 16; ++s) {
        f16x4 ev = *(const f16x4*)&myE[s * ESTRIDE + lane * 4];
        const float iz = invZs[s];
        float4 pv;
        pv.x = (float)ev[0] * iz; pv.y = (float)ev[1] * iz;
        pv.z = (float)ev[2] * iz; pv.w = (float)ev[3] * iz;
        *(float4*)(prow + (size_t)s * NSKV) = pv;
        csum[0] += pv.x; csum[1] += pv.y; csum[2] += pv.z; csum[3] += pv.w;
    }
    #pragma unroll
    for (int j = 0; j < 4; ++j)
        atomicAdd(&colsum[b * NSKV + h * 256 + lane * 4 + j], csum[j]);
}

// out[b,d] = sum_k colsum[b,k] * V[b,k,d]; 1024 blocks, 16 k-rows each.
__global__ __launch_bounds__(256) void attn_out_kernel(
    const float* __restrict__ colsum, const float* __restrict__ V,
    float* __restrict__ out)
{
    const int b  = blockIdx.x >> 6;
    const int ks = (blockIdx.x & 63) << 4;
    const int d  = threadIdx.x;
    float acc = 0.f;
    #pragma unroll
    for (int k = 0; k < 16; ++k) {
        acc += colsum[b * NSKV + ks + k] * V[((size_t)(b * NSKV + ks + k)) * ND + d];
    }
    atomicAdd(&out[b * ND + d], acc);
}

extern "C" void kernel_launch(void* const* d_in, const int* in_sizes, int n_in,
                              void* d_out, int out_size, void* d_ws, size_t ws_size,
                              hipStream_t stream)
{
    (void)in_sizes; (void)n_in; (void)out_size; (void)ws_size;
    const float* Q    = (const float*)d_in[0];
    const float* K    = (const float*)d_in[1];
    const float* V    = (const float*)d_in[2];
    const int*   mask = (const int*)d_in[3];

    float* out0 = (float*)d_out;            // (B, D) = 4096 floats
    float* p    = out0 + NB * ND;           // p_attn (B, SQ, SKV)

    float*    colsum = (float*)d_ws;                               // 64 KB
    __bf16*   Kb     = (__bf16*)((char*)d_ws + (64 << 10));        // 8.4 MB
    unsigned* mwbits = (unsigned*)((char*)d_ws + (64 << 10) + (size_t)NB * NSKV * ND * 2); // 4.2 MB

    hipMemsetAsync(colsum, 0, NB * NSKV * sizeof(float), stream);
    hipMemsetAsync(out0, 0, NB * ND * sizeof(float), stream);

    const int nK8 = NB * NSKV * ND / 8;
    cvt_k_bf16<<<nK8 / 256, 256, 0, stream>>>(K, Kb);
    pack_mask<<<NB * NSQ / 4, 256, 0, stream>>>(mask, mwbits);
    attn_fused<<<NB * 64, 256, 0, stream>>>(Q, Kb, mwbits, p, colsum);
    attn_out_kernel<<<NB * 64, 256, 0, stream>>>(colsum, V, out0);
}

// Round 6
// 236.631 us; speedup vs baseline: 1.1769x; 1.0116x over previous
//
#include <hip/hip_runtime.h>

#define NB   16
#define NSQ  1024
#define NSKV 1024
#define ND   256

typedef __bf16    bf16x8 __attribute__((ext_vector_type(8)));
typedef float     f32x4  __attribute__((ext_vector_type(4)));
typedef _Float16  f16x4  __attribute__((ext_vector_type(4)));

#define ESTRIDE 264   // f16 elems per e-row (256 + 8 pad)

// ---- prep 1: K (f32) -> bf16 row-major ----
__global__ __launch_bounds__(256) void cvt_k_bf16(
    const float* __restrict__ src, __bf16* __restrict__ dst)
{
    const int i = blockIdx.x * 256 + threadIdx.x;
    const float4* s = (const float4*)src + (size_t)i * 2;
    float4 a = s[0], b = s[1];
    bf16x8 o;
    o[0] = (__bf16)a.x; o[1] = (__bf16)a.y; o[2] = (__bf16)a.z; o[3] = (__bf16)a.w;
    o[4] = (__bf16)b.x; o[5] = (__bf16)b.y; o[6] = (__bf16)b.z; o[7] = (__bf16)b.w;
    ((bf16x8*)dst)[i] = o;
}

// ---- prep 2: pack mask to bits ----
// mw[row*64 + h*16 + m], bit c = (mask[row][h*256 + c*16 + m] != 0).
__global__ __launch_bounds__(256) void pack_mask(
    const int* __restrict__ mask, unsigned* __restrict__ mw)
{
    const int row = blockIdx.x * 4 + (threadIdx.x >> 6);   // b*NSQ + q
    const int l   = threadIdx.x & 63;
    const int4* mrow = (const int4*)(mask + (size_t)row * NSKV) + l * 4;
    unsigned w = 0;
    #pragma unroll
    for (int v = 0; v < 4; ++v) {
        int4 mv = mrow[v];
        w |= (mv.x != 0 ? 1u : 0u) << (v * 4 + 0);
        w |= (mv.y != 0 ? 1u : 0u) << (v * 4 + 1);
        w |= (mv.z != 0 ? 1u : 0u) << (v * 4 + 2);
        w |= (mv.w != 0 ? 1u : 0u) << (v * 4 + 3);
    }
    const int m    = l & 15;
    const int base = l & 48;
    unsigned out = 0;
    #pragma unroll
    for (int c = 0; c < 16; ++c) {
        unsigned v = (unsigned)__shfl((int)w, base | c);
        out |= ((v >> m) & 1u) << c;
    }
    mw[(size_t)row * 64 + l] = out;
}

// ---- main fused kernel ----
// Block = 256 thr (4 waves) = one 16-q-row tile; wave h owns k-quarter.
// Hot loop is a NON-unrolled, explicitly double-buffered pipeline: the 8
// B-fragment loads for chunk c+1 are issued BEFORE the MFMAs on chunk c,
// so each wave always has 8 loads in flight (vmcnt(8)-style waits) while
// 16 waves/CU provide TLP on top. e parked in LDS (f16); one barrier for
// the Z combine; p written as full 1KB contiguous segments per wave.
__global__ __launch_bounds__(256, 4) void attn_fused(
    const float* __restrict__ Q, const __bf16* __restrict__ Kb,
    const unsigned* __restrict__ mw, float* __restrict__ out_p,
    float* __restrict__ colsum)
{
    const int b    = blockIdx.x >> 6;
    const int qt   = blockIdx.x & 63;
    const int q0   = qt * 16;
    const int tid  = threadIdx.x;
    const int lane = tid & 63;
    const int h    = tid >> 6;       // wave id = k-quarter
    const int m    = lane & 15;      // MFMA A-row / B-col / C-col
    const int kg   = lane >> 4;      // quad: d-slice for A/B, row-group for C

    __shared__ _Float16 Es[4][16 * ESTRIDE];   // per-wave e tile (16 x 256)
    __shared__ float    Zs[4][16];
    __shared__ float    invZs[16];

    // ---- A fragments: the block's 16 Q rows, f32 -> bf16 once ----
    bf16x8 afrag[8];
    {
        const float* qbase = Q + ((size_t)(b * NSQ + q0 + m)) * ND;
        #pragma unroll
        for (int dc = 0; dc < 8; ++dc) {
            const float* p4 = qbase + dc * 32 + kg * 8;
            float4 x = *(const float4*)(p4);
            float4 y = *(const float4*)(p4 + 4);
            bf16x8 a;
            a[0] = (__bf16)x.x; a[1] = (__bf16)x.y; a[2] = (__bf16)x.z; a[3] = (__bf16)x.w;
            a[4] = (__bf16)y.x; a[5] = (__bf16)y.y; a[6] = (__bf16)y.z; a[7] = (__bf16)y.w;
            afrag[dc] = a;
        }
    }

    // ---- mask words: 4 per lane, covers the whole loop ----
    unsigned mword[4];
    #pragma unroll
    for (int i = 0; i < 4; ++i)
        mword[i] = mw[(size_t)(b * NSQ + q0 + kg * 4 + i) * 64 + h * 16 + m];

    const __bf16* kbase = Kb + ((size_t)(b * NSKV + h * 256 + m)) * ND + kg * 8;
    _Float16* myE = Es[h];

    float zacc[4] = {0.f, 0.f, 0.f, 0.f};

    // ---- prologue: load chunk 0 fragments ----
    bf16x8 cur[8], nxt[8];
    #pragma unroll
    for (int dc = 0; dc < 8; ++dc)
        cur[dc] = *(const bf16x8*)(kbase + dc * 32);

    #pragma unroll 1
    for (int c = 0; c < 16; ++c) {
        // issue next chunk's loads first (stay in flight across the MFMAs)
        const int cn = (c + 1) & 15;
        const __bf16* krow = kbase + (size_t)(cn * 16) * ND;
        #pragma unroll
        for (int dc = 0; dc < 8; ++dc)
            nxt[dc] = *(const bf16x8*)(krow + dc * 32);

        f32x4 acc = {0.f, 0.f, 0.f, 0.f};
        #pragma unroll
        for (int dc = 0; dc < 8; ++dc)
            acc = __builtin_amdgcn_mfma_f32_16x16x32_bf16(cur[dc], afrag[dc], acc, 0, 0, 0) ,
            acc = acc;  // keep sequence simple
        // NOTE: operand order (B-as-A) irrelevant? -- no, keep original order:
        // (the line above is rewritten below correctly; compiler removes dead code)
        acc = (f32x4){0.f, 0.f, 0.f, 0.f};
        #pragma unroll
        for (int dc = 0; dc < 8; ++dc)
            acc = __builtin_amdgcn_mfma_f32_16x16x32_bf16(afrag[dc], cur[dc], acc, 0, 0, 0);

        #pragma unroll
        for (int i = 0; i < 4; ++i) {
            float e = ((mword[i] >> c) & 1u) ? __expf(__expf(acc[i]) * 0.0625f) : 0.f;
            zacc[i] += e;
            myE[(kg * 4 + i) * ESTRIDE + c * 16 + m] = (_Float16)e;
        }

        #pragma unroll
        for (int dc = 0; dc < 8; ++dc)
            cur[dc] = nxt[dc];
    }

    // ---- Z: reduce over 16 m-lanes, publish per-wave partials ----
    #pragma unroll
    for (int i = 0; i < 4; ++i) {
        float z = zacc[i];
        z += __shfl_xor(z, 1);
        z += __shfl_xor(z, 2);
        z += __shfl_xor(z, 4);
        z += __shfl_xor(z, 8);
        if (m == 0) Zs[h][kg * 4 + i] = z;
    }
    __syncthreads();
    if (tid < 16)
        invZs[tid] = 1.0f / (Zs[0][tid] + Zs[1][tid] + Zs[2][tid] + Zs[3][tid]);
    __syncthreads();

    // ---- write phase: full 1KB contiguous stores; colsum in-pass ----
    float csum[4] = {0.f, 0.f, 0.f, 0.f};
    float* prow = out_p + (size_t)(b * NSQ + q0) * NSKV + h * 256 + lane * 4;
    #pragma unroll
    for (int s = 0; s < 16; ++s) {
        f16x4 ev = *(const f16x4*)&myE[s * ESTRIDE + lane * 4];
        const float iz = invZs[s];
        float4 pv;
        pv.x = (float)ev[0] * iz; pv.y = (float)ev[1] * iz;
        pv.z = (float)ev[2] * iz; pv.w = (float)ev[3] * iz;
        *(float4*)(prow + (size_t)s * NSKV) = pv;
        csum[0] += pv.x; csum[1] += pv.y; csum[2] += pv.z; csum[3] += pv.w;
    }
    #pragma unroll
    for (int j = 0; j < 4; ++j)
        atomicAdd(&colsum[b * NSKV + h * 256 + lane * 4 + j], csum[j]);
}

// out[b,d] = sum_k colsum[b,k] * V[b,k,d]; 1024 blocks, 16 k-rows each.
__global__ __launch_bounds__(256) void attn_out_kernel(
    const float* __restrict__ colsum, const float* __restrict__ V,
    float* __restrict__ out)
{
    const int b  = blockIdx.x >> 6;
    const int ks = (blockIdx.x & 63) << 4;
    const int d  = threadIdx.x;
    float acc = 0.f;
    #pragma unroll
    for (int k = 0; k < 16; ++k) {
        acc += colsum[b * NSKV + ks + k] * V[((size_t)(b * NSKV + ks + k)) * ND + d];
    }
    atomicAdd(&out[b * ND + d], acc);
}

extern "C" void kernel_launch(void* const* d_in, const int* in_sizes, int n_in,
                              void* d_out, int out_size, void* d_ws, size_t ws_size,
                              hipStream_t stream)
{
    (void)in_sizes; (void)n_in; (void)out_size; (void)ws_size;
    const float* Q    = (const float*)d_in[0];
    const float* K    = (const float*)d_in[1];
    const float* V    = (const float*)d_in[2];
    const int*   mask = (const int*)d_in[3];

    float* out0 = (float*)d_out;            // (B, D) = 4096 floats
    float* p    = out0 + NB * ND;           // p_attn (B, SQ, SKV)

    float*    colsum = (float*)d_ws;                               // 64 KB
    __bf16*   Kb     = (__bf16*)((char*)d_ws + (64 << 10));        // 8.4 MB
    unsigned* mwbits = (unsigned*)((char*)d_ws + (64 << 10) + (size_t)NB * NSKV * ND * 2); // 4.2 MB

    hipMemsetAsync(colsum, 0, NB * NSKV * sizeof(float), stream);
    hipMemsetAsync(out0, 0, NB * ND * sizeof(float), stream);

    const int nK8 = NB * NSKV * ND / 8;
    cvt_k_bf16<<<nK8 / 256, 256, 0, stream>>>(K, Kb);
    pack_mask<<<NB * NSQ / 4, 256, 0, stream>>>(mask, mwbits);
    attn_fused<<<NB * 64, 256, 0, stream>>>(Q, Kb, mwbits, p, colsum);
    attn_out_kernel<<<NB * 64, 256, 0, stream>>>(colsum, V, out0);
}

// Round 7
// 208.384 us; speedup vs baseline: 1.3364x; 1.1356x over previous
//
#include <hip/hip_runtime.h>

#define NB   16
#define NSQ  1024
#define NSKV 1024
#define ND   256

typedef __bf16    bf16x8 __attribute__((ext_vector_type(8)));
typedef float     f32x4  __attribute__((ext_vector_type(4)));
typedef _Float16  f16x4  __attribute__((ext_vector_type(4)));

#define KST 264   // LDS K-row stride in bf16 elems (528 B; 16B-aligned, conflict-min)

// ---- prep 1: K (f32) -> bf16 row-major ----
__global__ __launch_bounds__(256) void cvt_k_bf16(
    const float* __restrict__ src, __bf16* __restrict__ dst)
{
    const int i = blockIdx.x * 256 + threadIdx.x;
    const float4* s = (const float4*)src + (size_t)i * 2;
    float4 a = s[0], b = s[1];
    bf16x8 o;
    o[0] = (__bf16)a.x; o[1] = (__bf16)a.y; o[2] = (__bf16)a.z; o[3] = (__bf16)a.w;
    o[4] = (__bf16)b.x; o[5] = (__bf16)b.y; o[6] = (__bf16)b.z; o[7] = (__bf16)b.w;
    ((bf16x8*)dst)[i] = o;
}

// ---- prep 2: pack mask to bits ----
// mw[row*64 + h*16 + m], bit c = (mask[row][h*256 + c*16 + m] != 0).
__global__ __launch_bounds__(256) void pack_mask(
    const int* __restrict__ mask, unsigned* __restrict__ mw)
{
    const int row = blockIdx.x * 4 + (threadIdx.x >> 6);   // b*NSQ + q
    const int l   = threadIdx.x & 63;
    const int4* mrow = (const int4*)(mask + (size_t)row * NSKV) + l * 4;
    unsigned w = 0;
    #pragma unroll
    for (int v = 0; v < 4; ++v) {
        int4 mv = mrow[v];
        w |= (mv.x != 0 ? 1u : 0u) << (v * 4 + 0);
        w |= (mv.y != 0 ? 1u : 0u) << (v * 4 + 1);
        w |= (mv.z != 0 ? 1u : 0u) << (v * 4 + 2);
        w |= (mv.w != 0 ? 1u : 0u) << (v * 4 + 3);
    }
    const int m    = l & 15;
    const int base = l & 48;
    unsigned out = 0;
    #pragma unroll
    for (int c = 0; c < 16; ++c) {
        unsigned v = (unsigned)__shfl((int)w, base | c);
        out |= ((v >> m) & 1u) << c;
    }
    mw[(size_t)row * 64 + l] = out;
}

// ---- main fused kernel ----
// Block = 256 thr (4 waves) = one 16-q-row tile; wave h owns k-quarter.
// m97-style pipeline, wave-private (NO barriers in main loop): K chunk c+2
// global loads issue while chunk c computes from LDS and chunk c+1's landed
// registers are ds_written to the other LDS buffer. The ds_write/ds_read
// boundary is opaque to compiler sinking -> the pipeline cannot collapse.
// e parks in regs (f16x4[16]); after the loop the staging LDS is reused as
// the transpose buffer for coalesced 1KB p-stores.
__global__ __launch_bounds__(256, 2) void attn_fused(
    const float* __restrict__ Q, const __bf16* __restrict__ Kb,
    const unsigned* __restrict__ mw, float* __restrict__ out_p,
    float* __restrict__ colsum)
{
    const int b    = blockIdx.x >> 6;
    const int qt   = blockIdx.x & 63;
    const int q0   = qt * 16;
    const int tid  = threadIdx.x;
    const int lane = tid & 63;
    const int h    = tid >> 6;       // wave id = k-quarter
    const int m    = lane & 15;      // MFMA A-row / B-col / C-col
    const int kg   = lane >> 4;      // quad: d-slice for A/B, row-group for C

    __shared__ __attribute__((aligned(16))) __bf16 kbuf[4][2][16 * KST]; // 67.6 KB
    __shared__ float Zs[4][16];
    __shared__ float invZs[16];

    // ---- A fragments: the block's 16 Q rows, f32 -> bf16 once ----
    bf16x8 afrag[8];
    {
        const float* qbase = Q + ((size_t)(b * NSQ + q0 + m)) * ND;
        #pragma unroll
        for (int dc = 0; dc < 8; ++dc) {
            const float* p4 = qbase + dc * 32 + kg * 8;
            float4 x = *(const float4*)(p4);
            float4 y = *(const float4*)(p4 + 4);
            bf16x8 a;
            a[0] = (__bf16)x.x; a[1] = (__bf16)x.y; a[2] = (__bf16)x.z; a[3] = (__bf16)x.w;
            a[4] = (__bf16)y.x; a[5] = (__bf16)y.y; a[6] = (__bf16)y.z; a[7] = (__bf16)y.w;
            afrag[dc] = a;
        }
    }

    // ---- mask words: 4 per lane, covers the whole loop ----
    unsigned mword[4];
    #pragma unroll
    for (int i = 0; i < 4; ++i)
        mword[i] = mw[(size_t)(b * NSQ + q0 + kg * 4 + i) * 64 + h * 16 + m];

    // staging geometry: lane stages 8 x 16B; rows 2r + (lane>>5), col (lane&31)*8
    const __bf16* kq   = Kb + ((size_t)(b * NSKV + h * 256)) * ND;
    const int     gcol = (lane & 31) * 8;
    const int     grow = lane >> 5;
    __bf16* buf0 = &kbuf[h][0][0];
    __bf16* buf1 = &kbuf[h][1][0];

    float zacc[4] = {0.f, 0.f, 0.f, 0.f};
    f16x4 ebuf[16];
    bf16x8 ga[8], gb[8];

    #define LDCHUNK(g, c) { \
        const __bf16* _p = kq + (size_t)(c) * 16 * ND + gcol; \
        _Pragma("unroll") \
        for (int r = 0; r < 8; ++r) \
            (g)[r] = *(const bf16x8*)(_p + (size_t)(2 * r + grow) * ND); }

    #define STCHUNK(g, buf) { \
        _Pragma("unroll") \
        for (int r = 0; r < 8; ++r) \
            *(bf16x8*)((buf) + (2 * r + grow) * KST + gcol) = (g)[r]; }

    #define COMPUTE(buf, c) { \
        f32x4 acc = {0.f, 0.f, 0.f, 0.f}; \
        _Pragma("unroll") \
        for (int dc = 0; dc < 8; ++dc) { \
            bf16x8 bfr = *(const bf16x8*)((buf) + m * KST + dc * 32 + kg * 8); \
            acc = __builtin_amdgcn_mfma_f32_16x16x32_bf16(afrag[dc], bfr, acc, 0, 0, 0); \
        } \
        _Pragma("unroll") \
        for (int i = 0; i < 4; ++i) { \
            float e = ((mword[i] >> (c)) & 1u) ? __expf(__expf(acc[i]) * 0.0625f) : 0.f; \
            zacc[i] += e; \
            ebuf[c][i] = (_Float16)e; \
        } }

    // prologue: chunk0 -> buf0; chunk1 in flight
    LDCHUNK(ga, 0);
    STCHUNK(ga, buf0);
    LDCHUNK(gb, 1);

    #pragma unroll
    for (int cc = 0; cc < 16; cc += 2) {
        COMPUTE(buf0, cc);
        STCHUNK(gb, buf1);                       // chunk cc+1 (landed ~1 chunk ago)
        if (cc + 2 < 16) LDCHUNK(ga, cc + 2);
        COMPUTE(buf1, cc + 1);
        if (cc + 2 < 16) STCHUNK(ga, buf0);      // chunk cc+2
        if (cc + 3 < 16) LDCHUNK(gb, cc + 3);
    }

    // ---- park e into (now free) own-wave staging LDS for coalesced stores ----
    _Float16* myE = (_Float16*)&kbuf[h][0][0];   // 16 x 264 f16 = 8448 B fits buf0
    #pragma unroll
    for (int c = 0; c < 16; ++c)
        #pragma unroll
        for (int i = 0; i < 4; ++i)
            myE[(kg * 4 + i) * KST + c * 16 + m] = ebuf[c][i];

    // ---- Z: reduce over 16 m-lanes, publish per-wave partials ----
    #pragma unroll
    for (int i = 0; i < 4; ++i) {
        float z = zacc[i];
        z += __shfl_xor(z, 1);
        z += __shfl_xor(z, 2);
        z += __shfl_xor(z, 4);
        z += __shfl_xor(z, 8);
        if (m == 0) Zs[h][kg * 4 + i] = z;
    }
    __syncthreads();
    if (tid < 16)
        invZs[tid] = 1.0f / (Zs[0][tid] + Zs[1][tid] + Zs[2][tid] + Zs[3][tid]);
    __syncthreads();

    // ---- write phase: full 1KB contiguous stores; colsum in-pass ----
    const size_t rowbase = (size_t)(b * NSQ + q0);
    float csum[4] = {0.f, 0.f, 0.f, 0.f};
    float* prow = out_p + rowbase * NSKV + h * 256 + lane * 4;
    #pragma unroll
    for (int s = 0; s < 16; ++s) {
        f16x4 ev = *(const f16x4*)&myE[s * KST + lane * 4];
        const float iz = invZs[s];
        float4 pv;
        pv.x = (float)ev[0] * iz; pv.y = (float)ev[1] * iz;
        pv.z = (float)ev[2] * iz; pv.w = (float)ev[3] * iz;
        *(float4*)(prow + (size_t)s * NSKV) = pv;
        csum[0] += pv.x; csum[1] += pv.y; csum[2] += pv.z; csum[3] += pv.w;
    }
    #pragma unroll
    for (int j = 0; j < 4; ++j)
        atomicAdd(&colsum[b * NSKV + h * 256 + lane * 4 + j], csum[j]);
}

// out[b,d] = sum_k colsum[b,k] * V[b,k,d]; 1024 blocks, 16 k-rows each.
__global__ __launch_bounds__(256) void attn_out_kernel(
    const float* __restrict__ colsum, const float* __restrict__ V,
    float* __restrict__ out)
{
    const int b  = blockIdx.x >> 6;
    const int ks = (blockIdx.x & 63) << 4;
    const int d  = threadIdx.x;
    float acc = 0.f;
    #pragma unroll
    for (int k = 0; k < 16; ++k) {
        acc += colsum[b * NSKV + ks + k] * V[((size_t)(b * NSKV + ks + k)) * ND + d];
    }
    atomicAdd(&out[b * ND + d], acc);
}

extern "C" void kernel_launch(void* const* d_in, const int* in_sizes, int n_in,
                              void* d_out, int out_size, void* d_ws, size_t ws_size,
                              hipStream_t stream)
{
    (void)in_sizes; (void)n_in; (void)out_size; (void)ws_size;
    const float* Q    = (const float*)d_in[0];
    const float* K    = (const float*)d_in[1];
    const float* V    = (const float*)d_in[2];
    const int*   mask = (const int*)d_in[3];

    float* out0 = (float*)d_out;            // (B, D) = 4096 floats
    float* p    = out0 + NB * ND;           // p_attn (B, SQ, SKV)

    float*    colsum = (float*)d_ws;                               // 64 KB
    __bf16*   Kb     = (__bf16*)((char*)d_ws + (64 << 10));        // 8.4 MB
    unsigned* mwbits = (unsigned*)((char*)d_ws + (64 << 10) + (size_t)NB * NSKV * ND * 2); // 4.2 MB

    hipMemsetAsync(colsum, 0, NB * NSKV * sizeof(float), stream);
    hipMemsetAsync(out0, 0, NB * ND * sizeof(float), stream);

    const int nK8 = NB * NSKV * ND / 8;
    cvt_k_bf16<<<nK8 / 256, 256, 0, stream>>>(K, Kb);
    pack_mask<<<NB * NSQ / 4, 256, 0, stream>>>(mask, mwbits);
    attn_fused<<<NB * 64, 256, 0, stream>>>(Q, Kb, mwbits, p, colsum);
    attn_out_kernel<<<NB * 64, 256, 0, stream>>>(colsum, V, out0);
}